// Round 8
// baseline (435.372 us; speedup 1.0000x reference)
//
#include <hip/hip_runtime.h>
#include <hip/hip_bf16.h>
#include <stdint.h>

#define N_DIM 4
#define FIN 32
#define FOUT 64
#define ROWLEN 128   // FIN * N_DIM
#define NBLK 256     // edge chunks for the counting sort
#define BMAX 512     // max buckets (rows/256), M <= 131072
#define MAXE 20      // bsort: register-staged entries per thread (<=5120/bucket)

typedef __attribute__((ext_vector_type(4))) float f32x4;
typedef __attribute__((ext_vector_type(8))) short bf16x8;

__device__ __forceinline__ ushort f32_to_bf16_rn(float f) {
  uint u = __float_as_uint(f);
  u += 0x7FFFu + ((u >> 16) & 1u);     // round-to-nearest-even
  return (ushort)(u >> 16);
}
__device__ __forceinline__ float bf16_lo(uint p) { return __uint_as_float(p << 16); }
__device__ __forceinline__ float bf16_hi(uint p) { return __uint_as_float(p & 0xFFFF0000u); }
__device__ __forceinline__ uint pack2(float a, float b) {
  return (uint)f32_to_bf16_rn(a) | ((uint)f32_to_bf16_rn(b) << 16);
}

// ---------------------------------------------------------------------------
// 1. Fused: transpose x[N][M][Fin] -> Tb0[m][n*32+f] (bf16)  +  bcount
//    (blocks [0,tblocks) transpose; blocks [tblocks, tblocks+NBLK) histogram)
// ---------------------------------------------------------------------------
__global__ __launch_bounds__(256) void trans_count_kernel(
    const float* __restrict__ x, ushort* __restrict__ Tb0, int M, int tblocks,
    const int* __restrict__ rows, int* __restrict__ c, int E, int B, int ce) {
  __shared__ int hist[BMAX];
  if (blockIdx.x >= (unsigned)tblocks) {
    int blk = blockIdx.x - tblocks;
    int tid = threadIdx.x;
    for (int b = tid; b < B; b += 256) hist[b] = 0;
    __syncthreads();
    int start = blk * ce;
    int end = min(E, start + ce);
    for (int e = start + tid; e < end; e += 256)
      atomicAdd(&hist[rows[e] >> 8], 1);
    __syncthreads();
    for (int b = tid; b < B; b += 256) c[b * NBLK + blk] = hist[b];
    return;
  }
  int i = blockIdx.x * blockDim.x + threadIdx.x;
  if (i >= M * 16) return;
  int m = i >> 4;
  int n = (i >> 2) & 3;
  int f8 = i & 3;
  const float* src = x + ((size_t)n * M + m) * FIN + f8 * 8;
  float4 v0 = *reinterpret_cast<const float4*>(src);
  float4 v1 = *reinterpret_cast<const float4*>(src + 4);
  ushort h[8];
  h[0] = f32_to_bf16_rn(v0.x); h[1] = f32_to_bf16_rn(v0.y);
  h[2] = f32_to_bf16_rn(v0.z); h[3] = f32_to_bf16_rn(v0.w);
  h[4] = f32_to_bf16_rn(v1.x); h[5] = f32_to_bf16_rn(v1.y);
  h[6] = f32_to_bf16_rn(v1.z); h[7] = f32_to_bf16_rn(v1.w);
  *reinterpret_cast<uint4*>(Tb0 + (size_t)m * ROWLEN + n * 32 + f8 * 8) =
      *reinterpret_cast<const uint4*>(h);
}

// ---------------------------------------------------------------------------
// 2. CSR build — two-level counting sort with block-private regions.
// ---------------------------------------------------------------------------
__global__ __launch_bounds__(256) void bscanA_kernel(
    int* __restrict__ c, int* __restrict__ btot) {
  __shared__ int wsum[4];
  int b = blockIdx.x, tid = threadIdx.x;
  int lane = tid & 63, wid = tid >> 6;
  int v = c[b * NBLK + tid];
  int s = v;
#pragma unroll
  for (int off = 1; off < 64; off <<= 1) {
    int u = __shfl_up(s, off);
    if (lane >= off) s += u;
  }
  if (lane == 63) wsum[wid] = s;
  __syncthreads();
  if (tid == 0) {
    int run = 0;
#pragma unroll
    for (int w = 0; w < 4; ++w) { int t = wsum[w]; wsum[w] = run; run += t; }
  }
  __syncthreads();
  int excl = wsum[wid] + s - v;
  c[b * NBLK + tid] = excl;
  if (tid == 255) btot[b] = excl + v;
}

__global__ __launch_bounds__(512) void bscanB_kernel(
    const int* __restrict__ btot, int* __restrict__ bucket_start,
    int* __restrict__ row_start, int B, int M, int E) {
  __shared__ int wsum[8];
  int tid = threadIdx.x, lane = tid & 63, wid = tid >> 6;
  int v = (tid < B) ? btot[tid] : 0;
  int s = v;
#pragma unroll
  for (int off = 1; off < 64; off <<= 1) {
    int u = __shfl_up(s, off);
    if (lane >= off) s += u;
  }
  if (lane == 63) wsum[wid] = s;
  __syncthreads();
  if (tid == 0) {
    int run = 0;
#pragma unroll
    for (int w = 0; w < 8; ++w) { int t = wsum[w]; wsum[w] = run; run += t; }
  }
  __syncthreads();
  int excl = wsum[wid] + s - v;
  if (tid < B) bucket_start[tid] = excl;
  if (tid == 0) { bucket_start[B] = E; row_start[M] = E; }
}

__global__ __launch_bounds__(256) void bscatter_kernel(
    const int* __restrict__ rows, const int* __restrict__ cols,
    const float* __restrict__ vals, const int* __restrict__ c,
    const int* __restrict__ bucket_start, int2* __restrict__ binned,
    int E, int B, int ce) {
  __shared__ int base[BMAX];
  __shared__ int lcur[BMAX];
  int tid = threadIdx.x, blk = blockIdx.x;
  for (int b = tid; b < B; b += 256) {
    base[b] = bucket_start[b] + c[b * NBLK + blk];
    lcur[b] = 0;
  }
  __syncthreads();
  int start = blk * ce;
  int end = min(E, start + ce);
  for (int e = start + tid; e < end; e += 256) {
    int r = rows[e];
    int b = r >> 8;
    int pos = atomicAdd(&lcur[b], 1);
    binned[base[b] + pos] =
        make_int2(cols[e] | ((r & 255) << 17), __float_as_int(vals[e]));
  }
}

__global__ __launch_bounds__(256) void bsort_kernel(
    const int2* __restrict__ binned, const int* __restrict__ bucket_start,
    int2* __restrict__ csr, int* __restrict__ row_start, int M) {
  __shared__ int hist[256];
  __shared__ int wsum[4];
  int b = blockIdx.x, tid = threadIdx.x;
  int base = bucket_start[b];
  int cnt = bucket_start[b + 1] - base;
  hist[tid] = 0;
  __syncthreads();
  // register-staged bucket entries (static indexing)
  int2 en[MAXE];
#pragma unroll
  for (int k = 0; k < MAXE; ++k) {
    int i = tid + k * 256;
    if (i < cnt) {
      en[k] = binned[base + i];
      atomicAdd(&hist[((unsigned)en[k].x) >> 17], 1);
    }
  }
  for (int i = tid + MAXE * 256; i < cnt; i += 256)   // overflow fallback
    atomicAdd(&hist[((unsigned)binned[base + i].x) >> 17], 1);
  __syncthreads();
  int v = hist[tid];
  int lane = tid & 63, wid = tid >> 6;
  int s = v;
#pragma unroll
  for (int off = 1; off < 64; off <<= 1) {
    int u = __shfl_up(s, off);
    if (lane >= off) s += u;
  }
  if (lane == 63) wsum[wid] = s;
  __syncthreads();
  if (tid == 0) {
    int run = 0;
#pragma unroll
    for (int w = 0; w < 4; ++w) { int t = wsum[w]; wsum[w] = run; run += t; }
  }
  __syncthreads();
  int excl = wsum[wid] + s - v;
  int r = (b << 8) + tid;
  if (r < M) row_start[r] = base + excl;
  __syncthreads();
  hist[tid] = excl;
  __syncthreads();
#pragma unroll
  for (int k = 0; k < MAXE; ++k) {
    int i = tid + k * 256;
    if (i < cnt) {
      int rl = ((unsigned)en[k].x) >> 17;
      int p = atomicAdd(&hist[rl], 1);
      csr[base + p] = make_int2(en[k].x & 0x1FFFF, en[k].y);
    }
  }
  for (int i = tid + MAXE * 256; i < cnt; i += 256) {
    int2 e2 = binned[base + i];
    int rl = ((unsigned)e2.x) >> 17;
    int p = atomicAdd(&hist[rl], 1);
    csr[base + p] = make_int2(e2.x & 0x1FFFF, e2.y);
  }
}

// ---------------------------------------------------------------------------
// 3. SpMM — quarter-wave gather: 4 edges per VMEM instruction (uint4/lane,
//    16 lanes per 256B row), 2 groups (8 edges) in flight, persistent waves.
//    dstb[m,:] = bf16( alpha*Sum val*srcb[col] + beta*srcb[m] + gamma*prevb[m] )
// ---------------------------------------------------------------------------
#define GRP_LOAD(E0, E1, E2, E3, COL, V, J)                                  \
  E0 = csr[(J)];     E1 = csr[(J) + 1];                                      \
  E2 = csr[(J) + 2]; E3 = csr[(J) + 3];                                      \
  COL = qw == 0 ? E0.x : qw == 1 ? E1.x : qw == 2 ? E2.x : E3.x;             \
  V = __int_as_float(qw == 0 ? E0.y : qw == 1 ? E1.y : qw == 2 ? E2.y : E3.y);
#define GRP_GATH(G, COL)                                                     \
  G = *reinterpret_cast<const uint4*>(srcb + (size_t)(unsigned)(COL) * 64 +  \
                                      ql * 4);
#define GRP_CONS(G, V)                                                       \
  ac0 += (V)*bf16_lo(G.x); ac1 += (V)*bf16_hi(G.x);                          \
  ac2 += (V)*bf16_lo(G.y); ac3 += (V)*bf16_hi(G.y);                          \
  ac4 += (V)*bf16_lo(G.z); ac5 += (V)*bf16_hi(G.z);                          \
  ac6 += (V)*bf16_lo(G.w); ac7 += (V)*bf16_hi(G.w);

__global__ __launch_bounds__(256) void spmm_kernel(
    const uint* __restrict__ srcb, const uint* __restrict__ prevb,
    uint* __restrict__ dstb,
    const int* __restrict__ row_start, const int2* __restrict__ csr,
    int M, float alpha, float beta, float gamma, int nwt) {
  int lane = threadIdx.x & 63;
  int qw = lane >> 4;     // quarter-wave: which edge of the group
  int ql = lane & 15;     // lane within quarter: row uint4 index
  int gw0 = blockIdx.x * 4 + ((int)threadIdx.x >> 6);

  for (int gw = gw0; gw < M; gw += nwt) {
    int s = row_start[gw];
    int e = row_start[gw + 1];
    // self/prev rows issued early (independent of edge loop)
    uint4 sp4 = *reinterpret_cast<const uint4*>(srcb + (size_t)gw * 64 + ql * 4);
    uint4 pp4 = make_uint4(0, 0, 0, 0);
    if (prevb)
      pp4 = *reinterpret_cast<const uint4*>(prevb + (size_t)gw * 64 + ql * 4);

    float ac0 = 0.f, ac1 = 0.f, ac2 = 0.f, ac3 = 0.f;
    float ac4 = 0.f, ac5 = 0.f, ac6 = 0.f, ac7 = 0.f;
    int j = s;
    int rem = e - s;
    if (rem >= 8) {
      int2 a0, a1, a2, a3, b0, b1, b2, b3;
      int colA, colB;
      float vA, vB;
      uint4 gA, gB;
      GRP_LOAD(a0, a1, a2, a3, colA, vA, j); GRP_GATH(gA, colA);
      GRP_LOAD(b0, b1, b2, b3, colB, vB, j + 4); GRP_GATH(gB, colB);
      j += 8;
      for (; j + 8 <= e; j += 8) {
        GRP_CONS(gA, vA);
        GRP_LOAD(a0, a1, a2, a3, colA, vA, j); GRP_GATH(gA, colA);
        GRP_CONS(gB, vB);
        GRP_LOAD(b0, b1, b2, b3, colB, vB, j + 4); GRP_GATH(gB, colB);
      }
      if (j + 4 <= e) {
        GRP_CONS(gA, vA);
        GRP_LOAD(a0, a1, a2, a3, colA, vA, j); GRP_GATH(gA, colA);
        j += 4;
      }
      GRP_CONS(gA, vA);
      GRP_CONS(gB, vB);
    } else if (rem >= 4) {
      int2 a0, a1, a2, a3;
      int colA;
      float vA;
      uint4 gA;
      GRP_LOAD(a0, a1, a2, a3, colA, vA, j); GRP_GATH(gA, colA);
      j += 4;
      GRP_CONS(gA, vA);
    }
    if (j < e) {                       // masked tail group (1..3 edges)
      int idx = j + qw;
      int2 cv = csr[idx < e ? idx : (e - 1)];
      float v = (idx < e) ? __int_as_float(cv.y) : 0.f;
      uint4 g;
      GRP_GATH(g, cv.x);
      GRP_CONS(g, v);
    }

    // reduce partial sums across the 4 quarter-waves
#define RED(A) A += __shfl_xor(A, 16); A += __shfl_xor(A, 32);
    RED(ac0) RED(ac1) RED(ac2) RED(ac3) RED(ac4) RED(ac5) RED(ac6) RED(ac7)
#undef RED

    if (qw == 0) {
      ac0 = alpha * ac0 + beta * bf16_lo(sp4.x) + gamma * bf16_lo(pp4.x);
      ac1 = alpha * ac1 + beta * bf16_hi(sp4.x) + gamma * bf16_hi(pp4.x);
      ac2 = alpha * ac2 + beta * bf16_lo(sp4.y) + gamma * bf16_lo(pp4.y);
      ac3 = alpha * ac3 + beta * bf16_hi(sp4.y) + gamma * bf16_hi(pp4.y);
      ac4 = alpha * ac4 + beta * bf16_lo(sp4.z) + gamma * bf16_lo(pp4.z);
      ac5 = alpha * ac5 + beta * bf16_hi(sp4.z) + gamma * bf16_hi(pp4.z);
      ac6 = alpha * ac6 + beta * bf16_lo(sp4.w) + gamma * bf16_lo(pp4.w);
      ac7 = alpha * ac7 + beta * bf16_hi(sp4.w) + gamma * bf16_hi(pp4.w);
      uint4 o;
      o.x = pack2(ac0, ac1);
      o.y = pack2(ac2, ac3);
      o.z = pack2(ac4, ac5);
      o.w = pack2(ac6, ac7);
      *reinterpret_cast<uint4*>(dstb + (size_t)gw * 64 + ql * 4) = o;
    }
  }
}

// ---------------------------------------------------------------------------
// 4. Final GEMM via MFMA 16x16x32 bf16, no LDS (round-6 proven).
// ---------------------------------------------------------------------------
__global__ __launch_bounds__(256) void gemm_kernel(
    const ushort* __restrict__ Tb0, const ushort* __restrict__ Tb1,
    const ushort* __restrict__ Tb2, const ushort* __restrict__ Tb3,
    const float* __restrict__ W, float* __restrict__ out,
    int M, int nwaves) {
  int lane = threadIdx.x & 63;
  int gwave = blockIdx.x * 4 + ((int)threadIdx.x >> 6);
  int g = lane >> 4;   // 0..3: kappa-chunk group / store vertex
  int q = lane & 15;   // A row within tile / output column within fo-tile

  bf16x8 b[4][4];
#pragma unroll
  for (int t = 0; t < 4; ++t) {
#pragma unroll
    for (int ft = 0; ft < 4; ++ft) {
#pragma unroll
      for (int e = 0; e < 8; ++e) {
        float w = W[((8 * g + e) * 4 + t) * FOUT + ft * 16 + q];
        b[t][ft][e] = (short)f32_to_bf16_rn(w);
      }
    }
  }

  int NT = (M + 3) >> 2;
  for (int tile = gwave; tile < NT; tile += nwaves) {
    int m0 = tile * 4;
    int mA = m0 + (q >> 2);
    if (mA > M - 1) mA = M - 1;      // clamp; garbage rows are store-guarded
    int n = q & 3;
    size_t abase = (size_t)mA * ROWLEN + n * 32 + g * 8;

    f32x4 C0 = {0.f, 0.f, 0.f, 0.f};
    f32x4 C1 = C0, C2 = C0, C3 = C0;
#pragma unroll
    for (int t = 0; t < 4; ++t) {
      const ushort* Tb = t == 0 ? Tb0 : t == 1 ? Tb1 : t == 2 ? Tb2 : Tb3;
      bf16x8 a = *reinterpret_cast<const bf16x8*>(Tb + abase);  // 16B aligned
      C0 = __builtin_amdgcn_mfma_f32_16x16x32_bf16(a, b[t][0], C0, 0, 0, 0);
      C1 = __builtin_amdgcn_mfma_f32_16x16x32_bf16(a, b[t][1], C1, 0, 0, 0);
      C2 = __builtin_amdgcn_mfma_f32_16x16x32_bf16(a, b[t][2], C2, 0, 0, 0);
      C3 = __builtin_amdgcn_mfma_f32_16x16x32_bf16(a, b[t][3], C3, 0, 0, 0);
    }
    int mS = m0 + g;
    if (mS < M) {
#pragma unroll
      for (int r = 0; r < 4; ++r) {
        size_t ob = ((size_t)r * M + mS) * FOUT + q;
        out[ob +  0] = C0[r];
        out[ob + 16] = C1[r];
        out[ob + 32] = C2[r];
        out[ob + 48] = C3[r];
      }
    }
  }
}

// ---------------------------------------------------------------------------
extern "C" void kernel_launch(void* const* d_in, const int* in_sizes, int n_in,
                              void* d_out, int out_size, void* d_ws, size_t ws_size,
                              hipStream_t stream) {
  const float* x         = (const float*)d_in[0];
  const float* edge_vals = (const float*)d_in[1];
  const float* W         = (const float*)d_in[2];
  const int* edge_rows   = (const int*)d_in[3];
  const int* edge_cols   = (const int*)d_in[4];
  float* out = (float*)d_out;

  int M = in_sizes[0] / (N_DIM * FIN);
  int E = in_sizes[1];
  int B = (M + 255) >> 8;             // buckets of 256 rows
  int ce = (E + NBLK - 1) / NBLK;     // edges per chunk
  int tblocks = (M * 16 + 255) / 256;

  char* ws = (char*)d_ws;
  size_t rowf = (size_t)M * ROWLEN;
  ushort* Tb0 = (ushort*)ws;
  ushort* Tb1 = Tb0 + rowf;
  ushort* Tb2 = Tb1 + rowf;
  ushort* Tb3 = Tb2 + rowf;
  int2* binned = (int2*)(Tb3 + rowf);
  int2* csr = binned + E;
  int* c = (int*)(csr + E);                 // B*NBLK
  int* btot = c + (size_t)B * NBLK;         // B
  int* bucket_start = btot + B;             // B+1
  int* row_start = bucket_start + (B + 1);  // M+1

  trans_count_kernel<<<tblocks + NBLK, 256, 0, stream>>>(
      x, Tb0, M, tblocks, edge_rows, c, E, B, ce);
  bscanA_kernel<<<B, 256, 0, stream>>>(c, btot);
  bscanB_kernel<<<1, 512, 0, stream>>>(btot, bucket_start, row_start, B, M, E);
  bscatter_kernel<<<NBLK, 256, 0, stream>>>(edge_rows, edge_cols, edge_vals,
                                            c, bucket_start, binned, E, B, ce);
  bsort_kernel<<<B, 256, 0, stream>>>(binned, bucket_start, csr, row_start, M);

  int spmm_blocks = 2048;              // persistent: 8192 waves grid-stride
  int nwt = spmm_blocks * 4;
  // T1 = L'T0
  spmm_kernel<<<spmm_blocks, 256, 0, stream>>>(
      (const uint*)Tb0, nullptr, (uint*)Tb1, row_start, csr,
      M, 1.f, -1.f, 0.f, nwt);
  // T2 = 2L'T1 - T0
  spmm_kernel<<<spmm_blocks, 256, 0, stream>>>(
      (const uint*)Tb1, (const uint*)Tb0, (uint*)Tb2, row_start, csr,
      M, 2.f, -2.f, -1.f, nwt);
  // T3 = 2L'T2 - T1
  spmm_kernel<<<spmm_blocks, 256, 0, stream>>>(
      (const uint*)Tb2, (const uint*)Tb1, (uint*)Tb3, row_start, csr,
      M, 2.f, -2.f, -1.f, nwt);

  int gemm_blocks = 1024;  // 4096 waves, grid-stride over (M+3)/4 tiles
  gemm_kernel<<<gemm_blocks, 256, 0, stream>>>(
      Tb0, Tb1, Tb2, Tb3, W, out, M, gemm_blocks * 4);
}